// Round 2
// baseline (107.587 us; speedup 1.0000x reference)
//
#include <hip/hip_runtime.h>

#define TWO_PI 6.28318530717958647692f
// XOR-swizzle for float2 LDS arrays: nibble0 ^= nibble1.
// Verified conflict-free (b64 floor: 4 lanes/bank-pair) for all access phases
// of both the 4096-pt (old) and 2048-pt (new) exchanges.
#define SWZ(i) ((i) ^ (((i) >> 4) & 15))

// ---- elementwise float2 helpers ----
__device__ __forceinline__ float2 vadd(float2 a, float2 b) { return make_float2(a.x + b.x, a.y + b.y); }
__device__ __forceinline__ float2 vsub(float2 a, float2 b) { return make_float2(a.x - b.x, a.y - b.y); }
__device__ __forceinline__ float2 iperp(float2 z) { return make_float2(-z.y, z.x); }   // i*z

// a*b = b.x*a + b.y*(i*a)  -> 2 packed FMAs
__device__ __forceinline__ float2 cmul(float2 a, float2 b) {
    float2 p = iperp(a);
    return make_float2(fmaf(b.y, p.x, b.x * a.x), fmaf(b.y, p.y, b.x * a.y));
}

// z * (wr + i*S*wi), S compile-time sign
template<int SIGN>
__device__ __forceinline__ float2 twm(float2 z, float wr, float wi) {
    float2 p = iperp(z);
    const float swi = (SIGN > 0) ? wi : -wi;
    return make_float2(fmaf(swi, p.x, wr * z.x), fmaf(swi, p.y, wr * z.y));
}

// e^{S*i*th} for th in [0, 0.37]: Taylor, err < 2e-7 on this range. (legacy path)
__device__ __forceinline__ float2 eiw(float th, float S) {
    float t2 = th * th;
    float sn = th * (1.0f + t2 * (-1.0f / 6.0f + t2 * (1.0f / 120.0f)));
    float cs = 1.0f + t2 * (-0.5f + t2 * (1.0f / 24.0f + t2 * (-1.0f / 720.0f)));
    return make_float2(cs, S * sn);
}

// e^{+i*th} for th in [0, 0.79]: extended Taylor, err < 4e-7 on this range.
__device__ __forceinline__ float2 eiw2(float th) {
    float t2 = th * th;
    float sn = th * (1.0f + t2 * (-1.0f / 6.0f + t2 * (1.0f / 120.0f + t2 * (-1.0f / 5040.0f))));
    float cs = 1.0f + t2 * (-0.5f + t2 * (1.0f / 24.0f + t2 * (-1.0f / 720.0f + t2 * (1.0f / 40320.0f))));
    return make_float2(cs, sn);
}

// 4-pt butterfly core: inputs a,b,c,d -> ac,as,bd,ib (ib = SIGN*i*(b-d))
template<int SIGN>
__device__ __forceinline__ void bf4core(float2 a, float2 b, float2 c, float2 d,
                                        float2& ac, float2& as, float2& bd, float2& ib) {
    ac = vadd(a, c); as = vsub(a, c);
    bd = vadd(b, d);
    float2 bs = vsub(b, d);
    ib = (SIGN > 0) ? make_float2(-bs.y, bs.x) : make_float2(bs.y, -bs.x);
}

// 8-point DFT, in place: v[n] = sum_k v[k] exp(SIGN*2*pi*i*n*k/8)
template<int SIGN>
__device__ __forceinline__ void fft8(float2* v) {
    float2 ea, es, eb, ei_;
    bf4core<SIGN>(v[0], v[2], v[4], v[6], ea, es, eb, ei_);
    float2 A0 = vadd(ea, eb), A1 = vadd(es, ei_), A2 = vsub(ea, eb), A3 = vsub(es, ei_);
    float2 oa, os, ob, oi_;
    bf4core<SIGN>(v[1], v[3], v[5], v[7], oa, os, ob, oi_);
    float2 B0 = vadd(oa, ob), B1 = vadd(os, oi_), B2 = vsub(oa, ob), B3 = vsub(os, oi_);
    const float c2 = 0.70710678118654752f;
    B1 = twm<SIGN>(B1, c2, c2);                                        // W8^{S}
    B2 = (SIGN > 0) ? iperp(B2) : make_float2(B2.y, -B2.x);            // W8^{2S} = S*i
    B3 = twm<SIGN>(B3, -c2, c2);                                       // W8^{3S}
    v[0] = vadd(A0, B0); v[1] = vadd(A1, B1); v[2] = vadd(A2, B2); v[3] = vadd(A3, B3);
    v[4] = vsub(A0, B0); v[5] = vsub(A1, B1); v[6] = vsub(A2, B2); v[7] = vsub(A3, B3);
}

// 16-point DFT: out[n] = sum_k v[k] * exp(SIGN*2*pi*i*n*k/16), in-place.
// OUTSEL: 0 = all outputs; 1 = only v[4..11] (q=1,2); 2 = only v[0..7] (q=0,1).
template<int SIGN, int OUTSEL>
__device__ __forceinline__ void fft16(float2* v) {
    float2 t[16];
    #pragma unroll
    for (int k1 = 0; k1 < 4; ++k1) {           // 4-pt DFT over k2 (stride 4)
        float2 ac, as, bd, ib;
        bf4core<SIGN>(v[k1], v[k1 + 4], v[k1 + 8], v[k1 + 12], ac, as, bd, ib);
        t[k1 * 4 + 0] = vadd(ac, bd);
        t[k1 * 4 + 1] = vadd(as, ib);
        t[k1 * 4 + 2] = vsub(ac, bd);
        t[k1 * 4 + 3] = vsub(as, ib);
    }
    const float c1 = 0.92387953251128674f;     // cos(pi/8)
    const float s1 = 0.38268343236508977f;     // sin(pi/8)
    const float c2 = 0.70710678118654752f;     // cos(pi/4)
    t[5]  = twm<SIGN>(t[5],  c1,  s1);
    t[6]  = twm<SIGN>(t[6],  c2,  c2);
    t[7]  = twm<SIGN>(t[7],  s1,  c1);
    t[9]  = twm<SIGN>(t[9],  c2,  c2);
    t[10] = twm<SIGN>(t[10], 0.f, 1.f);
    t[11] = twm<SIGN>(t[11], -c2, c2);
    t[13] = twm<SIGN>(t[13], s1,  c1);
    t[14] = twm<SIGN>(t[14], -c2, c2);
    t[15] = twm<SIGN>(t[15], -c1, -s1);
    #pragma unroll
    for (int n2 = 0; n2 < 4; ++n2) {           // 4-pt DFT over k1 (stride 4 in t)
        float2 ac, as, bd, ib;
        bf4core<SIGN>(t[n2], t[4 + n2], t[8 + n2], t[12 + n2], ac, as, bd, ib);
        if (OUTSEL != 1) v[n2 + 0]  = vadd(ac, bd);          // q=0
        v[n2 + 4]  = vadd(as, ib);                           // q=1 (always needed)
        if (OUTSEL != 2) v[n2 + 8]  = vsub(ac, bd);          // q=2
        if (OUTSEL == 0) v[n2 + 12] = vsub(as, ib);          // q=3
    }
}

// 4096-pt DFT, 256 threads, radix-16 x3 through swizzled float2 LDS (32768 B).
// (legacy path, used by kfwd / kfused2)
template<int SIGN, int OUTSEL>
__device__ __forceinline__ void fft4096(float2* v, float2* s, int t) {
    const float S = (float)SIGN;
    {
        const int k1 = t & 15, k2 = t >> 4;
        fft16<SIGN, 0>(v);
        float2 w = eiw(TWO_PI * (float)k2 * (1.0f / 256.0f), S);
        float2 cur = make_float2(1.f, 0.f);
        #pragma unroll
        for (int n3 = 1; n3 < 16; ++n3) {
            cur = cmul(cur, w);
            v[n3] = cmul(v[n3], cur);
        }
        #pragma unroll
        for (int n3 = 0; n3 < 16; ++n3)
            s[SWZ(k2 * 256 + k1 * 16 + n3)] = v[n3];
    }
    __syncthreads();
    {
        const int n3 = t & 15, k1 = t >> 4;
        #pragma unroll
        for (int k2 = 0; k2 < 16; ++k2)
            v[k2] = s[SWZ(k2 * 256 + k1 * 16 + n3)];
        fft16<SIGN, 0>(v);
        float2 wb  = eiw(TWO_PI * (float)(n3 * k1) * (1.0f / 4096.0f), S);
        float2 wst = eiw(TWO_PI * (float)k1 * (1.0f / 256.0f), S);
        #pragma unroll
        for (int n2 = 0; n2 < 16; ++n2) {
            v[n2] = cmul(v[n2], wb);
            wb = cmul(wb, wst);
        }
        __syncthreads();
        #pragma unroll
        for (int n2 = 0; n2 < 16; ++n2)
            s[SWZ(k1 * 256 + n2 * 16 + n3)] = v[n2];
    }
    __syncthreads();
    {
        #pragma unroll
        for (int k1 = 0; k1 < 16; ++k1)
            v[k1] = s[SWZ(k1 * 256 + t)];
        fft16<SIGN, OUTSEL>(v);
    }
}

// 2048-pt inverse DFT core (SIGN=+1), 256 threads, 8 elems/thread,
// radices 8,8,8,(4 done by caller). LDS: float2[2048] = 16 KB.
// Input: v[k4] = Z[t + 256*k4]. After 3 stages+exchanges, caller does the
// final pruned 4-pt stage reading lines from s.
// Digits: k = k1 + 4*k2 + 32*k3 + 256*k4 ; n = n4 + 8*n3 + 64*n2 + 512*n1.
__device__ __forceinline__ void ifft2048_3stage(float2* v, float2* s, int t) {
    // ---- stage A: 8-pt over k4 -> n4 ; twiddle W2048^{t*n4} (t = k1+4k2+32k3)
    fft8<1>(v);
    {
        float2 w = eiw2(TWO_PI * (float)t * (1.0f / 2048.0f));
        float2 cur = w;
        v[1] = cmul(v[1], cur);
        #pragma unroll
        for (int n4 = 2; n4 < 8; ++n4) { cur = cmul(cur, w); v[n4] = cmul(v[n4], cur); }
        const int wbase = ((t >> 5) << 8) + ((t & 31) << 3);   // k3*256 + (k1+4k2)*8
        #pragma unroll
        for (int n4 = 0; n4 < 8; ++n4) s[SWZ(wbase + n4)] = v[n4];
    }
    __syncthreads();
    // ---- stage B: thread t = (k1+4k2)*8 + n4 ; 8-pt over k3 -> n3 ; twiddle W256^{(k1+4k2)*n3}
    {
        #pragma unroll
        for (int k3 = 0; k3 < 8; ++k3) v[k3] = s[SWZ(k3 * 256 + t)];
        fft8<1>(v);
        float2 w = eiw2(TWO_PI * (float)(t >> 3) * (1.0f / 256.0f));
        float2 cur = w;
        v[1] = cmul(v[1], cur);
        #pragma unroll
        for (int n3 = 2; n3 < 8; ++n3) { cur = cmul(cur, w); v[n3] = cmul(v[n3], cur); }
        __syncthreads();                       // all reads done before overwrite
        const int u = t >> 3, n4 = t & 7;
        const int wbase = (u >> 2) * 256 + (u & 3) * 64 + n4;  // k2*256 + k1*64 + n4
        #pragma unroll
        for (int n3 = 0; n3 < 8; ++n3) s[SWZ(wbase + n3 * 8)] = v[n3];
    }
    __syncthreads();
    // ---- stage C: thread t = k1*64 + n3*8 + n4 ; 8-pt over k2 -> n2 ; twiddle W32^{k1*n2}
    {
        #pragma unroll
        for (int k2 = 0; k2 < 8; ++k2) v[k2] = s[SWZ(k2 * 256 + t)];
        fft8<1>(v);
        float2 w = eiw2(TWO_PI * (float)(t >> 6) * (1.0f / 32.0f));
        float2 cur = w;
        v[1] = cmul(v[1], cur);
        #pragma unroll
        for (int n2 = 2; n2 < 8; ++n2) { cur = cmul(cur, w); v[n2] = cmul(v[n2], cur); }
        __syncthreads();
        const int wbase = (t >> 6) * 512 + (t & 63);           // k1*512 + (n3*8+n4)
        #pragma unroll
        for (int n2 = 0; n2 < 8; ++n2) s[SWZ(wbase + n2 * 64)] = v[n2];
    }
    __syncthreads();
    // stage D (4-pt over k1 -> n1, pruned) is done by the caller from s.
}

// Stage 1: forward FFT of reflect-padded x. xh[b*2048 + k], k in [0,2048).
__global__ __launch_bounds__(256) void kfwd(const float* __restrict__ x,
                                            float2* __restrict__ xh) {
    __shared__ float2 sbuf[4096];
    const int t = threadIdx.x, b = blockIdx.x;
    const float* xr = x + b * 2048;
    float2 v[16];
    #pragma unroll
    for (int k3 = 0; k3 < 16; ++k3) {
        int j = t + 256 * k3 - 1024;           // reflect pad
        j = (j < 0) ? -j : ((j >= 2048) ? (4094 - j) : j);
        j &= 2047;
        v[k3] = make_float2(xr[j], 0.0f);
    }
    fft4096<-1, 2>(v, sbuf, t);
    float2* xo = xh + b * 2048;
    #pragma unroll
    for (int n1 = 0; n1 < 8; ++n1)
        xo[t + 256 * n1] = v[n1];
}

// Stage 2 (real-split): one block per (b, scale). Real output row
// Re(ifft4096(Pa*Y)) computed via the even/odd pack: Z[k] = E[k] + i*W4096^k*O[k],
// z = ifft2048(Z), z[n'] = x[2n'] + i*x[2n'+1]. Crop [1024,3072) = z[512,1536).
// E[k] = c*(V[k] + conj(V[2048-k])), O[k] = c*(V[k] - conj(V[2048-k])),
// V[k] = Pa[k]*Y[k], c = 1/8192 (1/2 Hermitian * 1/2 split * 1/2048 iFFT).
// LDS 16 KB -> 8 blocks/CU (wave-limited, 100% occupancy target).
__global__ __launch_bounds__(256, 8) void kinvr(const float* __restrict__ Psih,
                                                const float2* __restrict__ xh,
                                                float* __restrict__ out,
                                                long long out_cap) {
    __shared__ float2 sbuf[2048];
    const int t = threadIdx.x;
    // XCD-chunked bijective swizzle: 8192 wgs, 8 XCDs -> each XCD gets a
    // contiguous chunk of the a-major ordering (32 scales x 32 batches:
    // Psih slice 512 KB + xh 512 KB resident per XCD L2).
    const int wg = blockIdx.x;
    const int idx = (wg & 7) * 1024 + (wg >> 3);
    const int a = idx >> 5, b = idx & 31;
    const float* pa = Psih + (size_t)a * 4096;
    const float2* xr = xh + (size_t)b * 2048;

    const float c1 = 0.92387953251128674f, s1 = 0.38268343236508977f, c2 = 0.70710678118654752f;
    const float W16r[8] = {1.f,  c1,  c2,  s1, 0.f, -s1, -c2, -c1};
    const float W16i[8] = {0.f,  s1,  c2,  c1, 1.f,  c1,  c2,  s1};
    const float c = 1.0f / 8192.0f;
    const float2 wt = eiw2(TWO_PI * (float)t * (1.0f / 4096.0f));

    float2 v[8];
    #pragma unroll
    for (int j = 0; j < 8; ++j) {
        const int k = t + 256 * j;             // [0,2048)
        const int m = 2048 - k;                // (0,2048]; Pa[2048]==0 kills m==2048
        float p1 = pa[k] * c;
        float p2 = pa[m] * c;
        float2 Y1 = xr[k];
        float2 Y2 = xr[m & 2047];              // mask no-op except m==2048 (p2==0)
        float Ex = fmaf(p2, Y2.x, p1 * Y1.x);
        float Ey = fmaf(-p2, Y2.y, p1 * Y1.y);
        float Ox = fmaf(-p2, Y2.x, p1 * Y1.x);
        float Oy = fmaf(p2, Y2.y, p1 * Y1.y);
        float2 w = cmul(wt, make_float2(W16r[j], W16i[j]));   // W4096^k
        // Z = E + i*(O*w)
        v[j] = make_float2(Ex - fmaf(Ox, w.y, Oy * w.x),
                           Ey + fmaf(Ox, w.x, -Oy * w.y));
    }
    ifft2048_3stage(v, sbuf, t);
    // ---- stage D: 4-pt over k1, lines L=t and L=t+256; keep n1=1,2 only.
    float2 la0 = sbuf[SWZ(t)],        la1 = sbuf[SWZ(512 + t)];
    float2 la2 = sbuf[SWZ(1024 + t)], la3 = sbuf[SWZ(1536 + t)];
    float2 lb0 = sbuf[SWZ(256 + t)],  lb1 = sbuf[SWZ(768 + t)];
    float2 lb2 = sbuf[SWZ(1280 + t)], lb3 = sbuf[SWZ(1792 + t)];
    float2 ac, as_, bd, ib;
    bf4core<1>(la0, la1, la2, la3, ac, as_, bd, ib);
    float2 z512  = vadd(as_, ib);              // n = 512 + t
    float2 z1024 = vsub(ac, bd);               // n = 1024 + t
    bf4core<1>(lb0, lb1, lb2, lb3, ac, as_, bd, ib);
    float2 z768  = vadd(as_, ib);              // n = 768 + t
    float2 z1280 = vsub(ac, bd);               // n = 1280 + t
    // out float2 index = n' - 512 ; row base (b*256+a)*1024 float2s
    const long long rowf = ((long long)b * 256 + a) * 2048;    // floats
    float2* orow = reinterpret_cast<float2*>(out) + ((size_t)b * 256 + a) * 1024;
    if (rowf + 2 * t + 1 < out_cap)            orow[t] = z512;
    if (rowf + 2 * (256 + t) + 1 < out_cap)    orow[256 + t] = z768;
    if (rowf + 2 * (512 + t) + 1 < out_cap)    orow[512 + t] = z1024;
    if (rowf + 2 * (768 + t) + 1 < out_cap)    orow[768 + t] = z1280;
}

// Fallback if workspace unusable: fused fwd+mul+inv, packed pairs (legacy).
__global__ __launch_bounds__(256) void kfused2(const float* __restrict__ x,
                                               const float* __restrict__ Psih,
                                               float* __restrict__ out,
                                               long long out_cap) {
    __shared__ float2 sbuf[4096];
    const int t = threadIdx.x;
    const int blk = blockIdx.x;
    const int ap = blk & 127, b = blk >> 7;
    const int a0 = ap * 2;
    const float* xr = x + b * 2048;
    float2 v[16];
    #pragma unroll
    for (int k3 = 0; k3 < 16; ++k3) {
        int j = t + 256 * k3 - 1024;
        j = (j < 0) ? -j : ((j >= 2048) ? (4094 - j) : j);
        j &= 2047;
        v[k3] = make_float2(xr[j], 0.0f);
    }
    fft4096<-1, 0>(v, sbuf, t);
    const float* pa = Psih + (size_t)a0 * 4096;
    const float* pb = pa + 4096;
    const float s = 0.5f / 4096.0f;
    #pragma unroll
    for (int n1 = 0; n1 < 16; ++n1) {
        int k = t + 256 * n1;
        int idx = (k < 2048) ? k : (4096 - k);
        float px = pa[idx] * s, py = pb[idx] * s;
        float2 X = v[n1];
        v[n1] = make_float2(px * X.x - py * X.y, py * X.x + px * X.y);
    }
    __syncthreads();
    fft4096<1, 1>(v, sbuf, t);
    const long long base = ((long long)b * 256 + a0) * 2048;
    #pragma unroll
    for (int n1 = 4; n1 < 12; ++n1) {
        long long oi = base + t + 256 * (n1 - 4);
        if (oi < out_cap) out[oi] = v[n1].x;
        long long oj = oi + 2048;
        if (oj < out_cap) out[oj] = v[n1].y;
    }
}

extern "C" void kernel_launch(void* const* d_in, const int* in_sizes, int n_in,
                              void* d_out, int out_size, void* d_ws, size_t ws_size,
                              hipStream_t stream) {
    const float* x = (const float*)d_in[0];
    const float* Psih = (const float*)d_in[1];
    float* out = (float*)d_out;
    const long long out_cap = (long long)out_size;   // float32 elements
    const size_t xh_bytes = (size_t)32 * 2048 * sizeof(float2);   // 512 KB
    if (ws_size >= xh_bytes && d_ws != nullptr) {
        float2* xh = (float2*)d_ws;
        kfwd<<<32, 256, 0, stream>>>(x, xh);
        kinvr<<<8192, 256, 0, stream>>>(Psih, xh, out, out_cap);
    } else {
        kfused2<<<4096, 256, 0, stream>>>(x, Psih, out, out_cap);
    }
}

// Round 3
// 105.765 us; speedup vs baseline: 1.0172x; 1.0172x over previous
//
#include <hip/hip_runtime.h>

#define TWO_PI 6.28318530717958647692f
// XOR-swizzle for float2 LDS arrays: nibble0 ^= nibble1.
// Verified conflict-free (b64 floor: 4 lanes/bank-pair) for all access phases
// of the 4096-pt (legacy) and the new 16x16x8 2048-pt exchanges.
#define SWZ(i) ((i) ^ (((i) >> 4) & 15))

// ---- elementwise float2 helpers ----
__device__ __forceinline__ float2 vadd(float2 a, float2 b) { return make_float2(a.x + b.x, a.y + b.y); }
__device__ __forceinline__ float2 vsub(float2 a, float2 b) { return make_float2(a.x - b.x, a.y - b.y); }
__device__ __forceinline__ float2 iperp(float2 z) { return make_float2(-z.y, z.x); }   // i*z

// a*b = b.x*a + b.y*(i*a)  -> 2 packed FMAs
__device__ __forceinline__ float2 cmul(float2 a, float2 b) {
    float2 p = iperp(a);
    return make_float2(fmaf(b.y, p.x, b.x * a.x), fmaf(b.y, p.y, b.x * a.y));
}

// z * (wr + i*S*wi), S compile-time sign
template<int SIGN>
__device__ __forceinline__ float2 twm(float2 z, float wr, float wi) {
    float2 p = iperp(z);
    const float swi = (SIGN > 0) ? wi : -wi;
    return make_float2(fmaf(swi, p.x, wr * z.x), fmaf(swi, p.y, wr * z.y));
}

// e^{S*i*th} for th in [0, 0.37]: Taylor, err < 2e-7 on this range. (legacy path)
__device__ __forceinline__ float2 eiw(float th, float S) {
    float t2 = th * th;
    float sn = th * (1.0f + t2 * (-1.0f / 6.0f + t2 * (1.0f / 120.0f)));
    float cs = 1.0f + t2 * (-0.5f + t2 * (1.0f / 24.0f + t2 * (-1.0f / 720.0f)));
    return make_float2(cs, S * sn);
}

// e^{+i*th} for th in [0, 0.79]: extended Taylor, err < 4e-7 on this range.
__device__ __forceinline__ float2 eiw2(float th) {
    float t2 = th * th;
    float sn = th * (1.0f + t2 * (-1.0f / 6.0f + t2 * (1.0f / 120.0f + t2 * (-1.0f / 5040.0f))));
    float cs = 1.0f + t2 * (-0.5f + t2 * (1.0f / 24.0f + t2 * (-1.0f / 720.0f + t2 * (1.0f / 40320.0f))));
    return make_float2(cs, sn);
}

// 4-pt butterfly core: inputs a,b,c,d -> ac,as,bd,ib (ib = SIGN*i*(b-d))
template<int SIGN>
__device__ __forceinline__ void bf4core(float2 a, float2 b, float2 c, float2 d,
                                        float2& ac, float2& as, float2& bd, float2& ib) {
    ac = vadd(a, c); as = vsub(a, c);
    bd = vadd(b, d);
    float2 bs = vsub(b, d);
    ib = (SIGN > 0) ? make_float2(-bs.y, bs.x) : make_float2(bs.y, -bs.x);
}

// 16-point DFT: out[n] = sum_k v[k] * exp(SIGN*2*pi*i*n*k/16), in-place.
// OUTSEL: 0 = all outputs; 1 = only v[4..11] (q=1,2); 2 = only v[0..7] (q=0,1).
template<int SIGN, int OUTSEL>
__device__ __forceinline__ void fft16(float2* v) {
    float2 t[16];
    #pragma unroll
    for (int k1 = 0; k1 < 4; ++k1) {           // 4-pt DFT over k2 (stride 4)
        float2 ac, as, bd, ib;
        bf4core<SIGN>(v[k1], v[k1 + 4], v[k1 + 8], v[k1 + 12], ac, as, bd, ib);
        t[k1 * 4 + 0] = vadd(ac, bd);
        t[k1 * 4 + 1] = vadd(as, ib);
        t[k1 * 4 + 2] = vsub(ac, bd);
        t[k1 * 4 + 3] = vsub(as, ib);
    }
    const float c1 = 0.92387953251128674f;     // cos(pi/8)
    const float s1 = 0.38268343236508977f;     // sin(pi/8)
    const float c2 = 0.70710678118654752f;     // cos(pi/4)
    t[5]  = twm<SIGN>(t[5],  c1,  s1);
    t[6]  = twm<SIGN>(t[6],  c2,  c2);
    t[7]  = twm<SIGN>(t[7],  s1,  c1);
    t[9]  = twm<SIGN>(t[9],  c2,  c2);
    t[10] = twm<SIGN>(t[10], 0.f, 1.f);
    t[11] = twm<SIGN>(t[11], -c2, c2);
    t[13] = twm<SIGN>(t[13], s1,  c1);
    t[14] = twm<SIGN>(t[14], -c2, c2);
    t[15] = twm<SIGN>(t[15], -c1, -s1);
    #pragma unroll
    for (int n2 = 0; n2 < 4; ++n2) {           // 4-pt DFT over k1 (stride 4 in t)
        float2 ac, as, bd, ib;
        bf4core<SIGN>(t[n2], t[4 + n2], t[8 + n2], t[12 + n2], ac, as, bd, ib);
        if (OUTSEL != 1) v[n2 + 0]  = vadd(ac, bd);          // q=0
        v[n2 + 4]  = vadd(as, ib);                           // q=1 (always needed)
        if (OUTSEL != 2) v[n2 + 8]  = vsub(ac, bd);          // q=2
        if (OUTSEL == 0) v[n2 + 12] = vsub(as, ib);          // q=3
    }
}

// 4096-pt DFT, 256 threads, radix-16 x3 through swizzled float2 LDS (32768 B).
// (legacy path, used by kfwd / kfused2)
template<int SIGN, int OUTSEL>
__device__ __forceinline__ void fft4096(float2* v, float2* s, int t) {
    const float S = (float)SIGN;
    {
        const int k1 = t & 15, k2 = t >> 4;
        fft16<SIGN, 0>(v);
        float2 w = eiw(TWO_PI * (float)k2 * (1.0f / 256.0f), S);
        float2 cur = make_float2(1.f, 0.f);
        #pragma unroll
        for (int n3 = 1; n3 < 16; ++n3) {
            cur = cmul(cur, w);
            v[n3] = cmul(v[n3], cur);
        }
        #pragma unroll
        for (int n3 = 0; n3 < 16; ++n3)
            s[SWZ(k2 * 256 + k1 * 16 + n3)] = v[n3];
    }
    __syncthreads();
    {
        const int n3 = t & 15, k1 = t >> 4;
        #pragma unroll
        for (int k2 = 0; k2 < 16; ++k2)
            v[k2] = s[SWZ(k2 * 256 + k1 * 16 + n3)];
        fft16<SIGN, 0>(v);
        float2 wb  = eiw(TWO_PI * (float)(n3 * k1) * (1.0f / 4096.0f), S);
        float2 wst = eiw(TWO_PI * (float)k1 * (1.0f / 256.0f), S);
        #pragma unroll
        for (int n2 = 0; n2 < 16; ++n2) {
            v[n2] = cmul(v[n2], wb);
            wb = cmul(wb, wst);
        }
        __syncthreads();
        #pragma unroll
        for (int n2 = 0; n2 < 16; ++n2)
            s[SWZ(k1 * 256 + n2 * 16 + n3)] = v[n2];
    }
    __syncthreads();
    {
        #pragma unroll
        for (int k1 = 0; k1 < 16; ++k1)
            v[k1] = s[SWZ(k1 * 256 + t)];
        fft16<SIGN, OUTSEL>(v);
    }
}

// Stage 1: forward FFT of reflect-padded x. xh[b*2048 + k], k in [0,2048).
__global__ __launch_bounds__(256) void kfwd(const float* __restrict__ x,
                                            float2* __restrict__ xh) {
    __shared__ float2 sbuf[4096];
    const int t = threadIdx.x, b = blockIdx.x;
    const float* xr = x + b * 2048;
    float2 v[16];
    #pragma unroll
    for (int k3 = 0; k3 < 16; ++k3) {
        int j = t + 256 * k3 - 1024;           // reflect pad
        j = (j < 0) ? -j : ((j >= 2048) ? (4094 - j) : j);
        j &= 2047;
        v[k3] = make_float2(xr[j], 0.0f);
    }
    fft4096<-1, 2>(v, sbuf, t);
    float2* xo = xh + b * 2048;
    #pragma unroll
    for (int n1 = 0; n1 < 8; ++n1)
        xo[t + 256 * n1] = v[n1];
}

// Stage 2 (real-split, 16x16x8): one block per (b, scale), 128 threads x 16 elems.
// Real output row Re(ifft4096(Pa*Y)) via even/odd pack: Z[k] = E[k] + i*W4096^k*O[k],
// z = ifft2048(Z), z[n'] = x[2n'] + i*x[2n'+1]. Crop [1024,3072) = z[512,1536).
// E[k] = c*(V[k] + conj(V[2048-k])), O[k] = c*(V[k] - conj(V[2048-k])), V = Pa*Y,
// c = 1/8192 (1/2 Hermitian * 1/2 split * 1/2048 iFFT).
// ifft2048: k = k1 + 8*k2 + 128*k3 (k1<8, k2<16, k3<16); n = n3 + 16*n2 + 256*n1.
//   S1: fft16 over k3 -> n3, twiddle W2048^{n3*t} (t = k1+8*k2)
//   S2: fft16 over k2 -> n2, twiddle W128^{k1*n2}
//   S3: radix-8 over k1 -> n1, pruned to n1 in {2..5} (the crop), reg->global.
// 2 LDS round-trips, 3 barriers (vs 3/5 in the previous 8,8,8,4 version).
// LDS 16 KB; 2-wave blocks, VGPR<=128 -> 8 blocks/CU.
__global__ __launch_bounds__(128, 4) void kinvr(const float* __restrict__ Psih,
                                                const float2* __restrict__ xh,
                                                float* __restrict__ out,
                                                long long out_cap) {
    __shared__ float2 sbuf[2048];
    const int t = threadIdx.x;                 // [0,128)
    // XCD-chunked bijective swizzle: 8192 wgs, 8 XCDs, a-major ordering ->
    // per-XCD working set: Psih slice 512 KB + xh 512 KB (L2-resident).
    const int wg = blockIdx.x;
    const int idx = (wg & 7) * 1024 + (wg >> 3);
    const int a = idx >> 5, b = idx & 31;
    const float* pa = Psih + (size_t)a * 4096;
    const float2* xr = xh + (size_t)b * 2048;

    // W32^j = e^{i*pi*j/16}, j in [0,16)
    const float W32r[16] = {
        1.0f, 0.98078528040323045f, 0.92387953251128676f, 0.83146961230254524f,
        0.70710678118654752f, 0.55557023301960222f, 0.38268343236508977f, 0.19509032201612827f,
        0.0f, -0.19509032201612827f, -0.38268343236508977f, -0.55557023301960222f,
        -0.70710678118654752f, -0.83146961230254524f, -0.92387953251128676f, -0.98078528040323045f };
    const float W32i[16] = {
        0.0f, 0.19509032201612827f, 0.38268343236508977f, 0.55557023301960222f,
        0.70710678118654752f, 0.83146961230254524f, 0.92387953251128676f, 0.98078528040323045f,
        1.0f, 0.98078528040323045f, 0.92387953251128676f, 0.83146961230254524f,
        0.70710678118654752f, 0.55557023301960222f, 0.38268343236508977f, 0.19509032201612827f };
    const float c = 1.0f / 8192.0f;
    const float2 wt = eiw2(TWO_PI * (float)t * (1.0f / 4096.0f));   // W4096^t, t<128

    float2 v[16];
    #pragma unroll
    for (int j = 0; j < 16; ++j) {             // k = t + 128*j in [0,2048)
        const int k = t + 128 * j;
        const int m = 2048 - k;                // (0,2048]; Pa[2048]==0 kills m==2048
        float p1 = pa[k] * c;
        float p2 = pa[m] * c;
        float2 Y1 = xr[k];
        float2 Y2 = xr[m & 2047];              // mask no-op except m==2048 (p2==0)
        float Ex = fmaf(p2, Y2.x, p1 * Y1.x);
        float Ey = fmaf(-p2, Y2.y, p1 * Y1.y);
        float Ox = fmaf(-p2, Y2.x, p1 * Y1.x);
        float Oy = fmaf(p2, Y2.y, p1 * Y1.y);
        float2 w = cmul(wt, make_float2(W32r[j], W32i[j]));   // W4096^k
        // Z = E + i*(O*w)
        v[j] = make_float2(Ex - fmaf(Ox, w.y, Oy * w.x),
                           Ey + fmaf(Ox, w.x, -Oy * w.y));
    }
    // ---- S1: fft16 over k3 -> n3 ; twiddle W2048^{n3*t} ; store (k2,k1,n3)
    fft16<1, 0>(v);
    {
        float2 w = eiw2(TWO_PI * (float)t * (1.0f / 2048.0f));   // t<128 -> th<0.39
        float2 cur = w;
        v[1] = cmul(v[1], cur);
        #pragma unroll
        for (int n3 = 2; n3 < 16; ++n3) { cur = cmul(cur, w); v[n3] = cmul(v[n3], cur); }
        const int k1 = t & 7, k2 = t >> 3;
        const int base = k2 * 128 + k1 * 16;
        #pragma unroll
        for (int n3 = 0; n3 < 16; ++n3) sbuf[SWZ(base + n3)] = v[n3];
    }
    __syncthreads();
    // ---- S2: thread (k1 = t>>4 in [0,8), n3 = t&15); fft16 over k2 -> n2 ;
    //          twiddle W128^{k1*n2} ; store (k1,n2,n3)
    {
        const int k1 = t >> 4, n3 = t & 15;
        #pragma unroll
        for (int k2 = 0; k2 < 16; ++k2) v[k2] = sbuf[SWZ(k2 * 128 + k1 * 16 + n3)];
        fft16<1, 0>(v);
        float2 w = eiw2(TWO_PI * (float)k1 * (1.0f / 128.0f));   // k1<8 -> th<0.35
        float2 cur = w;
        v[1] = cmul(v[1], cur);
        #pragma unroll
        for (int n2 = 2; n2 < 16; ++n2) { cur = cmul(cur, w); v[n2] = cmul(v[n2], cur); }
        __syncthreads();                       // all reads done before overwrite
        const int base = k1 * 256 + n3;
        #pragma unroll
        for (int n2 = 0; n2 < 16; ++n2) sbuf[SWZ(base + n2 * 16)] = v[n2];
    }
    __syncthreads();
    // ---- S3: two pruned radix-8 DFTs over k1, lines p = t and p = t+128.
    // Keep n1 in {2..5}; out float2 index = p + 256*(n1-2).
    float2* orow = reinterpret_cast<float2*>(out) + ((size_t)b * 256 + a) * 1024;
    const long long rowf = ((long long)b * 256 + a) * 2048;      // floats
    const float c2c = 0.70710678118654752f;
    #pragma unroll
    for (int h = 0; h < 2; ++h) {
        const int p = t + 128 * h;
        float2 u[8];
        #pragma unroll
        for (int k1 = 0; k1 < 8; ++k1) u[k1] = sbuf[SWZ(k1 * 256 + p)];
        float2 ea, es, eb, ei_;
        bf4core<1>(u[0], u[2], u[4], u[6], ea, es, eb, ei_);
        float2 A0 = vadd(ea, eb), A1 = vadd(es, ei_), A2 = vsub(ea, eb), A3 = vsub(es, ei_);
        float2 oa, os, ob, oi_;
        bf4core<1>(u[1], u[3], u[5], u[7], oa, os, ob, oi_);
        float2 B0 = vadd(oa, ob), B1 = vadd(os, oi_), B2 = vsub(oa, ob), B3 = vsub(os, oi_);
        B1 = twm<1>(B1, c2c, c2c);             // W8^1
        B2 = iperp(B2);                        // W8^2 = i
        B3 = twm<1>(B3, -c2c, c2c);            // W8^3
        float2 z2 = vadd(A2, B2);              // n1 = 2
        float2 z3 = vadd(A3, B3);              // n1 = 3
        float2 z4 = vsub(A0, B0);              // n1 = 4
        float2 z5 = vsub(A1, B1);              // n1 = 5
        if (rowf + 2 * (p + 0)   + 1 < out_cap) orow[p + 0]   = z2;
        if (rowf + 2 * (p + 256) + 1 < out_cap) orow[p + 256] = z3;
        if (rowf + 2 * (p + 512) + 1 < out_cap) orow[p + 512] = z4;
        if (rowf + 2 * (p + 768) + 1 < out_cap) orow[p + 768] = z5;
    }
}

// Fallback if workspace unusable: fused fwd+mul+inv, packed pairs (legacy).
__global__ __launch_bounds__(256) void kfused2(const float* __restrict__ x,
                                               const float* __restrict__ Psih,
                                               float* __restrict__ out,
                                               long long out_cap) {
    __shared__ float2 sbuf[4096];
    const int t = threadIdx.x;
    const int blk = blockIdx.x;
    const int ap = blk & 127, b = blk >> 7;
    const int a0 = ap * 2;
    const float* xr = x + b * 2048;
    float2 v[16];
    #pragma unroll
    for (int k3 = 0; k3 < 16; ++k3) {
        int j = t + 256 * k3 - 1024;
        j = (j < 0) ? -j : ((j >= 2048) ? (4094 - j) : j);
        j &= 2047;
        v[k3] = make_float2(xr[j], 0.0f);
    }
    fft4096<-1, 0>(v, sbuf, t);
    const float* pa = Psih + (size_t)a0 * 4096;
    const float* pb = pa + 4096;
    const float s = 0.5f / 4096.0f;
    #pragma unroll
    for (int n1 = 0; n1 < 16; ++n1) {
        int k = t + 256 * n1;
        int idx = (k < 2048) ? k : (4096 - k);
        float px = pa[idx] * s, py = pb[idx] * s;
        float2 X = v[n1];
        v[n1] = make_float2(px * X.x - py * X.y, py * X.x + px * X.y);
    }
    __syncthreads();
    fft4096<1, 1>(v, sbuf, t);
    const long long base = ((long long)b * 256 + a0) * 2048;
    #pragma unroll
    for (int n1 = 4; n1 < 12; ++n1) {
        long long oi = base + t + 256 * (n1 - 4);
        if (oi < out_cap) out[oi] = v[n1].x;
        long long oj = oi + 2048;
        if (oj < out_cap) out[oj] = v[n1].y;
    }
}

extern "C" void kernel_launch(void* const* d_in, const int* in_sizes, int n_in,
                              void* d_out, int out_size, void* d_ws, size_t ws_size,
                              hipStream_t stream) {
    const float* x = (const float*)d_in[0];
    const float* Psih = (const float*)d_in[1];
    float* out = (float*)d_out;
    const long long out_cap = (long long)out_size;   // float32 elements
    const size_t xh_bytes = (size_t)32 * 2048 * sizeof(float2);   // 512 KB
    if (ws_size >= xh_bytes && d_ws != nullptr) {
        float2* xh = (float2*)d_ws;
        kfwd<<<32, 256, 0, stream>>>(x, xh);
        kinvr<<<8192, 128, 0, stream>>>(Psih, xh, out, out_cap);
    } else {
        kfused2<<<4096, 256, 0, stream>>>(x, Psih, out, out_cap);
    }
}